// Round 5
// baseline (378.388 us; speedup 1.0000x reference)
//
#include <hip/hip_runtime.h>

// BilinearLayer: out = sigmoid( (E @ Bs_r) @ E^T ) per (b,r)
// B=8 R=8 N=1024 F=256.  All compute in f16 MFMA (16x16x32), fp32 accum.
//
// R5: FUSED gemm1+gemm2. Per block (br, 128-row n-block):
//   phase 1: e[128][256] = E_nblk @ Bs_r  -> LDS (64 KB, layout [gc32][n128][8])
//   phase 2: for 4 m-tiles of 256: scores = e @ E_mtile^T, sigmoid, store.
// Eliminates the 64 MB wse round-trip and one kernel launch; e is reused 4x
// from LDS. 512 thr / 8 waves, 128 KB LDS, 1 block/CU, grid 512 = 2 rounds.
// Fragment mappings identical to R4's verified gemm1/gemm2 (swapped-operand
// transposed-D epilogues). Register-staged loads (proven path, no gld_lds).
//
// ws layout (in _Float16 elements):
//   wsE   [64][32][1024][8] : E fp16, fragment layout [br][f/8][n][8]  (32 MB)
//   wsBsT [8][32][256][8]   : Bs^T fp16, [r][f/8][g][8]                (1 MB)

typedef float    f32x4 __attribute__((ext_vector_type(4)));
typedef _Float16 f16x8 __attribute__((ext_vector_type(8)));
typedef _Float16 f16x4 __attribute__((ext_vector_type(4)));

#define WS_E_OFF   0
#define WS_BST_OFF 16777216

// ---------------- kernel 0: convert / layout transform ----------------
__global__ __launch_bounds__(256) void bl_convert(
    const float* __restrict__ E, const float* __restrict__ Bs,
    _Float16* __restrict__ wsE, _Float16* __restrict__ wsBsT) {
  int bid = blockIdx.x, tid = threadIdx.x;
  if (bid < 8192) {
    // E: [br][n][f] fp32  ->  [br][fc][n][8] fp16
    int cid = (bid << 8) + tid;          // 2,097,152 chunks
    int br  = cid >> 15;
    int rem = cid & 32767;
    int fc  = rem >> 10;
    int n   = rem & 1023;                // n fast -> coalesced 16B writes
    const float* src = E + ((size_t)br << 18) + n * 256 + (fc << 3);
    f32x4 v0 = *(const f32x4*)src;
    f32x4 v1 = *(const f32x4*)(src + 4);
    f16x8 h;
    h[0] = (_Float16)v0[0]; h[1] = (_Float16)v0[1];
    h[2] = (_Float16)v0[2]; h[3] = (_Float16)v0[3];
    h[4] = (_Float16)v1[0]; h[5] = (_Float16)v1[1];
    h[6] = (_Float16)v1[2]; h[7] = (_Float16)v1[3];
    *(f16x8*)(wsE + ((size_t)br << 18) + (fc << 13) + (n << 3)) = h;
  } else {
    // Bs: [r][f][g] fp32 -> BsT fp16 [r][fc][g][8]  (transpose)
    int cid = ((bid - 8192) << 8) + tid; // 65,536 chunks
    int r   = cid >> 13;
    int rem = cid & 8191;
    int fc  = rem >> 8;
    int g   = rem & 255;                 // g fast -> coalesced reads per j
    const float* src = Bs + (r << 16) + (fc << 3) * 256 + g;
    f16x8 h;
#pragma unroll
    for (int j = 0; j < 8; ++j) h[j] = (_Float16)src[j * 256];
    *(f16x8*)(wsBsT + (r << 16) + (fc << 11) + (g << 3)) = h;
  }
}

// ---------------- fused kernel: e = E@Bs (LDS), out = sigmoid(e@E^T) --------
// grid: 64 br * 8 n-blocks = 512 blocks, 512 thr (8 waves), 128 KB LDS.
__global__ __launch_bounds__(512, 2) void bl_fused(
    const _Float16* __restrict__ wsE, const _Float16* __restrict__ wsBsT,
    float* __restrict__ out) {
  __shared__ _Float16 se[32768];    // 64 KB: e fragments [gc32][n128][8]
  __shared__ _Float16 stg[32768];   // 64 KB: ph1: E[0..8191]+Bs[8192..24575];
                                    //        ph2: 2 x 16384 (double buffer)
  int b0  = blockIdx.x;
  int bid = ((b0 & 7) << 6) + (b0 >> 3);   // XCD swizzle (512 = 8*64)
  int br  = bid >> 3;
  int nb  = bid & 7;
  int n0  = nb << 7;
  int r   = br & 7;
  int tid = threadIdx.x;
  int lane = tid & 63, wave = tid >> 6;    // 8 waves
  int quad = lane >> 4, l16 = lane & 15;
  int wg  = wave >> 1;                     // ph1 g-subtile / ph2 m-subtile (0..3)
  int wnn = wave & 1;                      // n-subtile (0..1)

  const _Float16* eG  = wsE + ((size_t)br << 18);
  const _Float16* bsG = wsBsT + (r << 16);

  f32x4 acc[4][4] = {};

  // ---------------- phase 1: e = E(n-block) @ Bs_r ----------------
  // wave tile 64g x 64n; D[g][n] (swapped operands, as R4 gemm1).
  for (int kk = 0; kk < 4; ++kk) {
    f16x8 va[2], vb[4];
#pragma unroll
    for (int i = 0; i < 2; ++i) {
      int c = (i << 9) + tid;            // 1024 chunks: E 128n x 64k
      int kcl = c >> 7, nl = c & 127;
      va[i] = *(const f16x8*)(eG + (((kk << 3) + kcl) << 13) + ((n0 + nl) << 3));
    }
#pragma unroll
    for (int i = 0; i < 4; ++i) {
      int c = (i << 9) + tid;            // 2048 chunks: BsT 256g x 64k
      int kcl = c >> 8, gl = c & 255;
      vb[i] = *(const f16x8*)(bsG + (((kk << 3) + kcl) << 11) + (gl << 3));
    }
    __syncthreads();                     // prior kk's readers done
#pragma unroll
    for (int i = 0; i < 2; ++i) {
      int c = (i << 9) + tid;
      *(f16x8*)&stg[c << 3] = va[i];
    }
#pragma unroll
    for (int i = 0; i < 4; ++i) {
      int c = (i << 9) + tid;
      *(f16x8*)&stg[8192 + (c << 3)] = vb[i];
    }
    __syncthreads();
#pragma unroll
    for (int ks = 0; ks < 2; ++ks) {
      int kc = (ks << 2) + quad;
      f16x8 af[4], bf[4];
#pragma unroll
      for (int rt = 0; rt < 4; ++rt)
        af[rt] = *(const f16x8*)&stg[((kc << 7) + (wnn << 6) + (rt << 4) + l16) << 3];
#pragma unroll
      for (int ct = 0; ct < 4; ++ct)
        bf[ct] = *(const f16x8*)&stg[8192 + (((kc << 8) + (wg << 6) + (ct << 4) + l16) << 3)];
#pragma unroll
      for (int rt = 0; rt < 4; ++rt)
#pragma unroll
        for (int ct = 0; ct < 4; ++ct)
          acc[rt][ct] = __builtin_amdgcn_mfma_f32_16x16x32_f16(bf[ct], af[rt], acc[rt][ct], 0, 0, 0);
    }
  }
  // e-epilogue -> se[gc][n][8]: per lane 4 consecutive g = 8B LDS store.
#pragma unroll
  for (int rt = 0; rt < 4; ++rt) {
    int n = (wnn << 6) + (rt << 4) + l16;        // local n 0..127
#pragma unroll
    for (int ct = 0; ct < 4; ++ct) {
      int g  = (wg << 6) + (ct << 4) + (quad << 2);
      int gc = g >> 3, gj = g & 7;               // gj in {0,4}
      f16x4 h;
#pragma unroll
      for (int i = 0; i < 4; ++i) h[i] = (_Float16)acc[rt][ct][i];
      *(f16x4*)&se[(gc << 10) + (n << 3) + gj] = h;
    }
  }

  // ---------------- phase 2: out = sigmoid(e @ E^T) ----------------
  // m-loop: 4 m-tiles of 256; wave tile 64m x 64n; D[m][n] (as R4 gemm2).
  // Double-buffered staging, ONE barrier per K-chunk.
  f16x8 vs[4];
#pragma unroll
  for (int i = 0; i < 4; ++i) {        // prologue: chunk (mt=0, kk=0)
    int c = (i << 9) + tid;
    int kcl = c >> 8, ml = c & 255;
    vs[i] = *(const f16x8*)(eG + (kcl << 13) + (ml << 3));
  }
#pragma unroll
  for (int rt = 0; rt < 4; ++rt)
#pragma unroll
    for (int ct = 0; ct < 4; ++ct) acc[rt][ct] = (f32x4){0.f, 0.f, 0.f, 0.f};
  __syncthreads();                     // phase boundary: ph1 stg readers + se writers done

  float* oB = out + ((size_t)br << 20);
  int buf = 0;
  for (int jj = 0; jj < 16; ++jj) {    // mt = jj>>2, kk = jj&3
    int kk = jj & 3;
#pragma unroll
    for (int i = 0; i < 4; ++i) {      // store staged chunk -> stg[buf]
      int c = (i << 9) + tid;
      *(f16x8*)&stg[(buf << 14) + (c << 3)] = vs[i];
    }
    __syncthreads();                   // writes visible; compute(jj-2) on buf long done
    if (jj < 15) {                     // prefetch next chunk into regs
      int j2 = jj + 1;
      int mt2 = j2 >> 2, kk2 = j2 & 3;
#pragma unroll
      for (int i = 0; i < 4; ++i) {
        int c = (i << 9) + tid;
        int kcl = c >> 8, ml = c & 255;
        vs[i] = *(const f16x8*)(eG + (((kk2 << 3) + kcl) << 13) + (((mt2 << 8) + ml) << 3));
      }
    }
#pragma unroll
    for (int ks = 0; ks < 2; ++ks) {
      int kc = (ks << 2) + quad;
      f16x8 af[4], bf[4];
#pragma unroll
      for (int rt = 0; rt < 4; ++rt)   // A(B-slot): e from se, k = global g-chunk
        af[rt] = *(const f16x8*)&se[((((kk << 3) + kc) << 7) + (wnn << 6) + (rt << 4) + l16) << 3];
#pragma unroll
      for (int ct = 0; ct < 4; ++ct)   // B(A-slot): E m-rows from stg[buf]
        bf[ct] = *(const f16x8*)&stg[(buf << 14) + (((kc << 8) + (wg << 6) + (ct << 4) + l16) << 3)];
#pragma unroll
      for (int rt = 0; rt < 4; ++rt)
#pragma unroll
        for (int ct = 0; ct < 4; ++ct)
          acc[rt][ct] = __builtin_amdgcn_mfma_f32_16x16x32_f16(bf[ct], af[rt], acc[rt][ct], 0, 0, 0);
    }
    if (kk == 3) {                     // m-tile epilogue: sigmoid + float4 store
      int mt = jj >> 2;
#pragma unroll
      for (int rt = 0; rt < 4; ++rt) {
        int n = n0 + (wnn << 6) + (rt << 4) + l16;
#pragma unroll
        for (int ct = 0; ct < 4; ++ct) {
          int m = (mt << 8) + (wg << 6) + (ct << 4) + (quad << 2);
          f32x4 v;
#pragma unroll
          for (int i = 0; i < 4; ++i) {
            float x = acc[rt][ct][i];
            v[i] = __builtin_amdgcn_rcpf(1.0f + __expf(-x));
          }
          *(f32x4*)(oB + ((size_t)n << 10) + m) = v;
          acc[rt][ct] = (f32x4){0.f, 0.f, 0.f, 0.f};
        }
      }
    }
    buf ^= 1;
  }
}

extern "C" void kernel_launch(void* const* d_in, const int* in_sizes, int n_in,
                              void* d_out, int out_size, void* d_ws, size_t ws_size,
                              hipStream_t stream) {
  const float* E  = (const float*)d_in[0];   // [8,8,1024,256]
  const float* Bs = (const float*)d_in[1];   // [8,256,256]
  _Float16* wsE   = (_Float16*)d_ws + WS_E_OFF;
  _Float16* wsBsT = (_Float16*)d_ws + WS_BST_OFF;
  float* out = (float*)d_out;

  bl_convert<<<8448, 256, 0, stream>>>(E, Bs, wsE, wsBsT);
  bl_fused<<<512, 512, 0, stream>>>(wsE, wsBsT, out);
}